// Round 6
// baseline (90.249 us; speedup 1.0000x reference)
//
#include <hip/hip_runtime.h>

// VectorQuantiser on MI355X — split pipeline, candidate-carrying GEMM.
// Inputs:  d_in[0] = z_e fp32 (16*2048*256), d_in[1] = codebook fp32 (1024*256)
// Outputs (flat fp32): z_q [8388608] | similarity [33554432] | ids [32768] | loss [1]
//
//   1 prep_cb:  codebook -> bf16 (ws) + nse + rsqe.
//   2 gemm:     128x128 tile bf16 MFMA. A reg-staged from fp32 (+row norms in-block),
//               B via global_load_lds from cbb (pre-swizzled source). Epilogue: sim
//               write + top-2-per-64-strip candidate encodings -> cand (4 MB, parked
//               in the z_q output slot, which is dead until zq_loss).
//   3 select1:  per row: 32 cand encs -> argmin; fp32-exact rescore of near-ties
//               (margin 2.0 ~ 20 sigma of bf16 est error); writes ids only.
//   4 zq_loss:  ids -> gather z_q (overwrites cand region, safe: stream-ordered
//               after select1), loss partials per block.
//   5 finalize: deterministic tree-sum of 8192 partials; loss = 1.25 * mean.

#define M_ROWS 32768
#define KCODES 1024
#define DDIM   256
#define ENC_BIG 33554432.0f

typedef __bf16 bf16_t;
typedef __attribute__((ext_vector_type(8))) bf16_t bf16x8;
typedef __attribute__((ext_vector_type(4))) float f32x4;

__device__ __forceinline__ unsigned f2bf(float f) {
  unsigned u = __float_as_uint(f);
  u += 0x7FFFu + ((u >> 16) & 1u);   // round-to-nearest-even
  return u >> 16;
}

__device__ __forceinline__ float wave_sum(float p) {
#pragma unroll
  for (int o = 1; o < 64; o <<= 1) p += __shfl_xor(p, o);
  return p;
}
__device__ __forceinline__ float wave_min(float p) {
#pragma unroll
  for (int o = 1; o < 64; o <<= 1) p = fminf(p, __shfl_xor(p, o));
  return p;
}

// ---------------- Kernel 1: codebook convert + norms ----------------
__global__ __launch_bounds__(256) void prep_cb_kernel(
    const float* __restrict__ cb, unsigned short* __restrict__ cbb,
    float* __restrict__ nse, float* __restrict__ rsqe)
{
  const int t = threadIdx.x;
  const int lane = t & 63;
  const int r = blockIdx.x * 4 + (t >> 6);           // wave per codebook row, 1024 rows
  const float4 e = ((const float4*)cb)[(size_t)r * 64 + lane];
  ushort4 u;
  u.x = (unsigned short)f2bf(e.x); u.y = (unsigned short)f2bf(e.y);
  u.z = (unsigned short)f2bf(e.z); u.w = (unsigned short)f2bf(e.w);
  ((ushort4*)cbb)[(size_t)r * 64 + lane] = u;
  float p = wave_sum(e.x*e.x + e.y*e.y + e.z*e.z + e.w*e.w);
  if (lane == 0) { nse[r] = p; rsqe[r] = 1.0f / sqrtf(p); }
}

// ---------------- Kernel 2: GEMM + sim + cand epilogue ----------------
__global__ __launch_bounds__(256, 2) void gemm_kernel(
    const float* __restrict__ ze, const unsigned short* __restrict__ cbb,
    const float* __restrict__ rsqe_g, const float* __restrict__ nse_g,
    float* __restrict__ sim, float* __restrict__ cand)
{
  __shared__ __attribute__((aligned(128))) unsigned short A[128 * 64];   // 16 KB swizzled
  __shared__ __attribute__((aligned(128))) unsigned short Bt[128 * 64];  // 16 KB swizzled
  __shared__ float s_rsqz[128];

  const int t = threadIdx.x;
  const int wv = t >> 6, lane = t & 63;
  const int bid = blockIdx.x;
  const int swz = (bid & 7) * 256 + (bid >> 3);      // XCD swizzle, nwg=2048 % 8 == 0
  const long row0 = (long)(swz >> 3) * 128;          // 256 row tiles
  const int  col0 = (swz & 7) * 128;                 // 8 col tiles

  f32x4 acc[4][4] = {};

  // B DMA pre-swizzle (validated round-2 path)
  const int rr = lane >> 3, qq = lane & 7;
  const int sq = ((qq ^ rr) << 3);

  // A reg-staging assignment: idx = i*256+t -> row = idx>>3 (0..127), quad = idx&7
  float nrm[4] = {0.f, 0.f, 0.f, 0.f};

  for (int kt = 0; kt < 4; ++kt) {
    const int k0 = kt * 64;
    // ---- B: 128 codes x 64 K via global_load_lds, pre-swizzled source ----
#pragma unroll
    for (int i = 0; i < 4; ++i) {
      const int rbase = wv * 32 + i * 8;
      const unsigned short* src = cbb + ((size_t)(col0 + rbase + rr)) * DDIM + k0 + sq;
      __builtin_amdgcn_global_load_lds((const __attribute__((address_space(1))) void*)src,
                                       (__attribute__((address_space(3))) void*)&Bt[rbase * 64],
                                       16, 0, 0);
    }
    // ---- A: 128 rows x 64 K reg-staged from fp32, convert + norm + swizzled write ----
#pragma unroll
    for (int i = 0; i < 4; ++i) {
      const int idx = i * 256 + t;
      const int ar = idx >> 3, aq = idx & 7;
      const float4* p = (const float4*)(ze + (row0 + ar) * (size_t)DDIM + k0 + aq * 8);
      const float4 x = p[0], y = p[1];
      nrm[i] += x.x*x.x + x.y*x.y + x.z*x.z + x.w*x.w
              + y.x*y.x + y.y*y.y + y.z*y.z + y.w*y.w;
      uint4 u;
      u.x = f2bf(x.x) | (f2bf(x.y) << 16);
      u.y = f2bf(x.z) | (f2bf(x.w) << 16);
      u.z = f2bf(y.x) | (f2bf(y.y) << 16);
      u.w = f2bf(y.z) | (f2bf(y.w) << 16);
      *(uint4*)((char*)A + ar * 128 + ((aq ^ (ar & 7)) << 4)) = u;
    }
    __syncthreads();                                 // A written, B DMA drained

    const int r16 = lane & 15, g = lane >> 4;
    const int wm = wv >> 1, wn = wv & 1;
#pragma unroll
    for (int ks = 0; ks < 2; ++ks) {
      bf16x8 af[4], bfr[4];
#pragma unroll
      for (int mi = 0; mi < 4; ++mi) {
        const int r = wm * 64 + mi * 16 + r16;
        const int ph = ((ks * 4 + g) ^ (r & 7)) << 4;
        af[mi] = *(const bf16x8*)((const char*)A + r * 128 + ph);
      }
#pragma unroll
      for (int ni = 0; ni < 4; ++ni) {
        const int r = wn * 64 + ni * 16 + r16;
        const int ph = ((ks * 4 + g) ^ (r & 7)) << 4;
        bfr[ni] = *(const bf16x8*)((const char*)Bt + r * 128 + ph);
      }
#pragma unroll
      for (int mi = 0; mi < 4; ++mi)
#pragma unroll
        for (int ni = 0; ni < 4; ++ni)
          acc[mi][ni] = __builtin_amdgcn_mfma_f32_16x16x32_bf16(af[mi], bfr[ni], acc[mi][ni], 0, 0, 0);
    }
    __syncthreads();                                 // protect A/Bt overwrite next kt
  }

  // ---- row norms -> s_rsqz (8 lanes per row hold the partials) ----
#pragma unroll
  for (int i = 0; i < 4; ++i) {
    float p = nrm[i];
    p += __shfl_xor(p, 1); p += __shfl_xor(p, 2); p += __shfl_xor(p, 4);
    if ((t & 7) == 0) s_rsqz[(i * 256 + t) >> 3] = 1.0f / sqrtf(p);
  }
  __syncthreads();

  // ---- epilogue: sim write + top-2 per 64-col strip candidates ----
  const int r16 = lane & 15, g = lane >> 4;
  const int wm = wv >> 1, wn = wv & 1;
  const int strip = (col0 >> 6) | wn;                // global strip 0..15
#pragma unroll
  for (int mi = 0; mi < 4; ++mi) {
#pragma unroll
    for (int j = 0; j < 4; ++j) {
      const int rloc = wm * 64 + mi * 16 + g * 4 + j;
      const long row = row0 + rloc;
      const float rz = s_rsqz[rloc];
      float* so = sim + (size_t)row * KCODES + col0 + wn * 64 + r16;
      float e1 = ENC_BIG, e2 = ENC_BIG;
#pragma unroll
      for (int ni = 0; ni < 4; ++ni) {
        const int colk = col0 + wn * 64 + ni * 16 + r16;
        const float d = acc[mi][ni][j];
        so[ni * 16] = d * rz * rsqe_g[colk];
        const float v = nse_g[colk] - 2.0f * d;
        const float enc = floorf((v + 1024.0f) * 8.0f) * 1024.0f + (float)colk;
        if (enc < e1) { e2 = e1; e1 = enc; } else e2 = fminf(e2, enc);
      }
#pragma unroll
      for (int m = 1; m < 16; m <<= 1) {             // top-2 across the 16-lane group
        const float p1 = __shfl_xor(e1, m);
        const float p2 = __shfl_xor(e2, m);
        const float n1 = fminf(e1, p1);
        const float n2 = fminf(fmaxf(e1, p1), fminf(e2, p2));
        e1 = n1; e2 = n2;
      }
      if (r16 == 0)
        ((float2*)cand)[row * 16 + strip] = make_float2(e1, e2);
    }
  }
}

// ---------------- Kernel 3: candidate argmin -> ids ----------------
__global__ __launch_bounds__(256) void select1_kernel(
    const float* __restrict__ ze, const float* __restrict__ cb,
    const float* __restrict__ cand, const float* __restrict__ nse,
    float* __restrict__ ids)
{
  const int t = threadIdx.x;
  const int lane = t & 63;
  const int row  = blockIdx.x * 4 + (t >> 6);        // wave per row

  const float e = (lane < 32) ? cand[(size_t)row * 32 + lane] : ENC_BIG;
  const float m_enc = wave_min(e);
  const float qmin  = floorf(m_enc * 0.0009765625f); // exact /1024
  const float ql    = floorf(e * 0.0009765625f);
  unsigned long long msk = __ballot(ql <= qmin + 16.0f);  // margin 2.0 dist units
  int kbest;
  if (__popcll(msk) == 1) {
    kbest = ((int)m_enc) & 1023;
  } else {
    const float4 zr = ((const float4*)ze)[(size_t)row * 64 + lane];
    float tbest = INFINITY; kbest = KCODES;
    while (msk) {                                    // wave-uniform
      const int lb = __ffsll(msk) - 1;
      msk &= msk - 1;
      const int kc = ((int)__shfl(e, lb)) & 1023;
      const float4 er = ((const float4*)cb)[(size_t)kc * 64 + lane];
      const float p = wave_sum(zr.x*er.x + zr.y*er.y + zr.z*er.z + zr.w*er.w);
      const float tv = nse[kc] - 2.0f * p;           // exact fp32 dist - nsz
      if (tv < tbest || (tv == tbest && kc < kbest)) { tbest = tv; kbest = kc; }
    }
  }
  if (lane == 0) ids[row] = (float)kbest;
}

// ---------------- Kernel 4: z_q gather + loss partials ----------------
__global__ __launch_bounds__(256) void zq_loss_kernel(
    const float* __restrict__ ze, const float* __restrict__ cb,
    const float* __restrict__ ids,
    float* __restrict__ zq, float* __restrict__ partials)
{
  __shared__ float s_part[4];
  const int t = threadIdx.x;
  const int wv = t >> 6, lane = t & 63;
  const int row = blockIdx.x * 4 + wv;

  const int kbest = (int)ids[row];
  const float4 er = ((const float4*)cb)[(size_t)kbest * 64 + lane];
  const float4 zr = ((const float4*)ze)[(size_t)row * 64 + lane];
  ((float4*)zq)[(size_t)row * 64 + lane] = er;
  const float dx = zr.x - er.x, dy = zr.y - er.y, dz = zr.z - er.z, dw = zr.w - er.w;
  const float ss = wave_sum(dx*dx + dy*dy + dz*dz + dw*dw);
  if (lane == 0) s_part[wv] = sqrtf(ss);
  __syncthreads();
  if (t == 0)
    partials[blockIdx.x] = (s_part[0] + s_part[1]) + (s_part[2] + s_part[3]);
}

// ---------------- Kernel 5: finalize loss (deterministic tree sum) ----------------
__global__ __launch_bounds__(256) void finalize_kernel(
    const float* __restrict__ partials, float* __restrict__ out_loss)
{
  __shared__ float s[4];
  const int t = threadIdx.x;
  float p = 0.0f;
#pragma unroll
  for (int i = 0; i < 32; ++i) p += partials[t + i * 256];  // 8192, fixed order
  p = wave_sum(p);
  if ((t & 63) == 0) s[t >> 6] = p;
  __syncthreads();
  if (t == 0) out_loss[0] = 1.25f * ((s[0] + s[1]) + (s[2] + s[3])) / 32768.0f;
}

extern "C" void kernel_launch(void* const* d_in, const int* in_sizes, int n_in,
                              void* d_out, int out_size, void* d_ws, size_t ws_size,
                              hipStream_t stream) {
  const float* ze = (const float*)d_in[0];
  const float* cb = (const float*)d_in[1];

  float* out  = (float*)d_out;
  float* zq   = out;                    // 8388608
  float* sim  = out + 8388608;          // 33554432
  float* ids  = out + 41943040;         // 32768
  float* lout = out + 41975808;         // 1

  // cand (4 MB = 32768 rows x 16 strips x float2) parked in the z_q slot:
  // written by gemm, read by select1, then legally overwritten by zq_loss.
  float* cand = zq;

  // ws layout (~565 KB, under the confirmed >=800 KB floor)
  char* w = (char*)d_ws;
  unsigned short* cbb = (unsigned short*)w;      // 512 KB
  float* nse      = (float*)(w + 524288);        // 4 KB
  float* rsqe     = (float*)(w + 528384);        // 4 KB
  float* partials = (float*)(w + 532480);        // 32 KB (8192 f32)

  prep_cb_kernel<<<256, 256, 0, stream>>>(cb, cbb, nse, rsqe);
  gemm_kernel<<<2048, 256, 0, stream>>>(ze, cbb, rsqe, nse, sim, cand);
  select1_kernel<<<8192, 256, 0, stream>>>(ze, cb, cand, nse, ids);
  zq_loss_kernel<<<8192, 256, 0, stream>>>(ze, cb, ids, zq, partials);
  finalize_kernel<<<1, 256, 0, stream>>>(partials, lout);
}

// Round 7
// 78.272 us; speedup vs baseline: 1.1530x; 1.1530x over previous
//
#include <hip/hip_runtime.h>

// VectorQuantiser on MI355X — split pipeline: validated-fast gemm (round 2) +
// validated-cheap candidate select tail (round 6).
// Inputs:  d_in[0] = z_e fp32 (16*2048*256), d_in[1] = codebook fp32 (1024*256)
// Outputs (flat fp32): z_q [8388608] | similarity [33554432] | ids [32768] | loss [1]
//
//   1 prep:     z_e -> bf16 zb (parked in z_q slot bytes [0,16.8M)); codebook ->
//               bf16 cbb (ws); rsqz / nse / rsqe.
//   2 gemm:     128x128 tile bf16 MFMA, A AND B via global_load_lds (pre-swizzled
//               source, XOR-swizzled LDS). Epilogue: sim write + top-2-per-64-strip
//               candidate encodings -> cand (4 MB, parked in z_q slot bytes
//               [16.8M, 20.8M) — disjoint from zb, dead until zq_loss).
//   3 select1:  per row: 32 cand encs -> argmin; fp32-exact rescore of near-ties
//               (margin 2.0); writes ids only.
//   4 zq_loss:  ids -> gather z_q (overwrites zb+cand region; stream-ordered after
//               select1), per-block loss partials.
//   5 finalize: deterministic tree-sum of 8192 partials; loss = 1.25 * mean.

#define M_ROWS 32768
#define KCODES 1024
#define DDIM   256
#define ENC_BIG 33554432.0f

typedef __bf16 bf16_t;
typedef __attribute__((ext_vector_type(8))) bf16_t bf16x8;
typedef __attribute__((ext_vector_type(4))) float f32x4;

__device__ __forceinline__ unsigned short f2bf(float f) {
  unsigned u = __float_as_uint(f);
  u += 0x7FFFu + ((u >> 16) & 1u);   // round-to-nearest-even
  return (unsigned short)(u >> 16);
}

__device__ __forceinline__ float wave_sum(float p) {
#pragma unroll
  for (int o = 1; o < 64; o <<= 1) p += __shfl_xor(p, o);
  return p;
}
__device__ __forceinline__ float wave_min(float p) {
#pragma unroll
  for (int o = 1; o < 64; o <<= 1) p = fminf(p, __shfl_xor(p, o));
  return p;
}

// ---------------- Kernel 1: convert + norms (round-2 prep) ----------------
__global__ __launch_bounds__(256) void prep_kernel(
    const float* __restrict__ ze, const float* __restrict__ cb,
    unsigned short* __restrict__ zb, unsigned short* __restrict__ cbb,
    float* __restrict__ rsqz,
    float* __restrict__ nse, float* __restrict__ rsqe)
{
  const int t = threadIdx.x;
  const int lane = t & 63;
  const int row = blockIdx.x * 4 + (t >> 6);         // wave per row; rows 0..33791
  if (row < M_ROWS) {
    const float4 z = ((const float4*)ze)[(size_t)row * 64 + lane];
    ushort4 u;
    u.x = f2bf(z.x); u.y = f2bf(z.y); u.z = f2bf(z.z); u.w = f2bf(z.w);
    ((ushort4*)zb)[(size_t)row * 64 + lane] = u;
    float p = wave_sum(z.x*z.x + z.y*z.y + z.z*z.z + z.w*z.w);
    if (lane == 0) rsqz[row] = 1.0f / sqrtf(p);
  } else {
    const int r = row - M_ROWS;                      // 0..1023
    const float4 e = ((const float4*)cb)[(size_t)r * 64 + lane];
    ushort4 u;
    u.x = f2bf(e.x); u.y = f2bf(e.y); u.z = f2bf(e.z); u.w = f2bf(e.w);
    ((ushort4*)cbb)[(size_t)r * 64 + lane] = u;
    float p = wave_sum(e.x*e.x + e.y*e.y + e.z*e.z + e.w*e.w);
    if (lane == 0) { nse[r] = p; rsqe[r] = 1.0f / sqrtf(p); }
  }
}

// ---------------- Kernel 2: GEMM (round-2) + sim + cand epilogue (round-6) ----------------
__global__ __launch_bounds__(256, 2) void gemm_kernel(
    const unsigned short* __restrict__ zb, const unsigned short* __restrict__ cbb,
    const float* __restrict__ rsqz, const float* __restrict__ rsqe_g,
    const float* __restrict__ nse_g,
    float* __restrict__ sim, float* __restrict__ cand)
{
  __shared__ __attribute__((aligned(128))) unsigned short lds[16384]; // A [0,8192), B [8192,16384)
  const int tid  = threadIdx.x;
  const int wv   = tid >> 6, lane = tid & 63;
  const int bid  = blockIdx.x;
  const int swz  = (bid & 7) * 256 + (bid >> 3);     // XCD swizzle, nwg=2048 % 8 == 0
  const long row0 = (long)(swz >> 3) * 128;          // 256 row tiles
  const int  col0 = (swz & 7) * 128;                 // 8 col tiles

  f32x4 acc[4][4] = {};

  const int rr = lane >> 3, qq = lane & 7;
  const int sq = ((qq ^ rr) << 3);                   // pre-swizzled source quad (16B)

  for (int kt = 0; kt < 4; ++kt) {
    const int k0 = kt * 64;
#pragma unroll
    for (int i = 0; i < 4; ++i) {
      const int rbase = wv * 32 + i * 8;
      const unsigned short* srca = zb  + ((size_t)(row0 + rbase + rr)) * DDIM + k0 + sq;
      const unsigned short* srcb = cbb + ((size_t)(col0 + rbase + rr)) * DDIM + k0 + sq;
      __builtin_amdgcn_global_load_lds((const __attribute__((address_space(1))) void*)srca,
                                       (__attribute__((address_space(3))) void*)&lds[rbase * 64],
                                       16, 0, 0);
      __builtin_amdgcn_global_load_lds((const __attribute__((address_space(1))) void*)srcb,
                                       (__attribute__((address_space(3))) void*)&lds[8192 + rbase * 64],
                                       16, 0, 0);
    }
    __syncthreads();
    const int r16 = lane & 15, g = lane >> 4;
#pragma unroll
    for (int ks = 0; ks < 2; ++ks) {
      bf16x8 af[4], bfr[4];
#pragma unroll
      for (int mi = 0; mi < 4; ++mi) {
        const int r  = (wv >> 1) * 64 + mi * 16 + r16;
        const int qy = ((ks * 4 + g) ^ (r & 7)) << 4;
        af[mi] = *(const bf16x8*)((const char*)lds + r * 128 + qy);
      }
#pragma unroll
      for (int ni = 0; ni < 4; ++ni) {
        const int r  = (wv & 1) * 64 + ni * 16 + r16;
        const int qy = ((ks * 4 + g) ^ (r & 7)) << 4;
        bfr[ni] = *(const bf16x8*)((const char*)lds + 16384 + r * 128 + qy);
      }
#pragma unroll
      for (int mi = 0; mi < 4; ++mi)
#pragma unroll
        for (int ni = 0; ni < 4; ++ni)
          acc[mi][ni] = __builtin_amdgcn_mfma_f32_16x16x32_bf16(af[mi], bfr[ni], acc[mi][ni], 0, 0, 0);
    }
    __syncthreads();
  }

  // Epilogue: sim write + top-2 per 64-col strip candidates.
  // C/D layout: col = lane&15, row = (lane>>4)*4 + j.
  const int r16 = lane & 15, g = lane >> 4;
  const int wm = wv >> 1, wn = wv & 1;
  const int strip = (col0 >> 6) | wn;                // global strip 0..15
#pragma unroll
  for (int mi = 0; mi < 4; ++mi) {
#pragma unroll
    for (int j = 0; j < 4; ++j) {
      const long row = row0 + wm * 64 + mi * 16 + g * 4 + j;
      const float rz = rsqz[row];
      float* so = sim + (size_t)row * KCODES + col0 + wn * 64 + r16;
      float e1 = ENC_BIG, e2 = ENC_BIG;
#pragma unroll
      for (int ni = 0; ni < 4; ++ni) {
        const int colk = col0 + wn * 64 + ni * 16 + r16;
        const float d = acc[mi][ni][j];
        so[ni * 16] = d * rz * rsqe_g[colk];
        const float v = nse_g[colk] - 2.0f * d;
        const float enc = floorf((v + 1024.0f) * 8.0f) * 1024.0f + (float)colk;
        if (enc < e1) { e2 = e1; e1 = enc; } else e2 = fminf(e2, enc);
      }
#pragma unroll
      for (int m = 1; m < 16; m <<= 1) {             // top-2 across the 16-lane group
        const float p1 = __shfl_xor(e1, m);
        const float p2 = __shfl_xor(e2, m);
        const float n1 = fminf(e1, p1);
        const float n2 = fminf(fmaxf(e1, p1), fminf(e2, p2));
        e1 = n1; e2 = n2;
      }
      if (r16 == 0)
        ((float2*)cand)[row * 16 + strip] = make_float2(e1, e2);
    }
  }
}

// ---------------- Kernel 3: candidate argmin -> ids ----------------
__global__ __launch_bounds__(256) void select1_kernel(
    const float* __restrict__ ze, const float* __restrict__ cb,
    const float* __restrict__ cand, const float* __restrict__ nse,
    float* __restrict__ ids)
{
  const int t = threadIdx.x;
  const int lane = t & 63;
  const int row  = blockIdx.x * 4 + (t >> 6);        // wave per row

  const float e = (lane < 32) ? cand[(size_t)row * 32 + lane] : ENC_BIG;
  const float m_enc = wave_min(e);
  const float qmin  = floorf(m_enc * 0.0009765625f); // exact /1024
  const float ql    = floorf(e * 0.0009765625f);
  unsigned long long msk = __ballot(ql <= qmin + 16.0f);  // margin 2.0 dist units
  int kbest;
  if (__popcll(msk) == 1) {
    kbest = ((int)m_enc) & 1023;
  } else {
    const float4 zr = ((const float4*)ze)[(size_t)row * 64 + lane];
    float tbest = INFINITY; kbest = KCODES;
    while (msk) {                                    // wave-uniform
      const int lb = __ffsll(msk) - 1;
      msk &= msk - 1;
      const int kc = ((int)__shfl(e, lb)) & 1023;
      const float4 er = ((const float4*)cb)[(size_t)kc * 64 + lane];
      const float p = wave_sum(zr.x*er.x + zr.y*er.y + zr.z*er.z + zr.w*er.w);
      const float tv = nse[kc] - 2.0f * p;           // exact fp32 dist - nsz
      if (tv < tbest || (tv == tbest && kc < kbest)) { tbest = tv; kbest = kc; }
    }
  }
  if (lane == 0) ids[row] = (float)kbest;
}

// ---------------- Kernel 4: z_q gather + loss partials ----------------
__global__ __launch_bounds__(256) void zq_loss_kernel(
    const float* __restrict__ ze, const float* __restrict__ cb,
    const float* __restrict__ ids,
    float* __restrict__ zq, float* __restrict__ partials)
{
  __shared__ float s_part[4];
  const int t = threadIdx.x;
  const int wv = t >> 6, lane = t & 63;
  const int row = blockIdx.x * 4 + wv;

  const int kbest = (int)ids[row];
  const float4 er = ((const float4*)cb)[(size_t)kbest * 64 + lane];
  const float4 zr = ((const float4*)ze)[(size_t)row * 64 + lane];
  ((float4*)zq)[(size_t)row * 64 + lane] = er;
  const float dx = zr.x - er.x, dy = zr.y - er.y, dz = zr.z - er.z, dw = zr.w - er.w;
  const float ss = wave_sum(dx*dx + dy*dy + dz*dz + dw*dw);
  if (lane == 0) s_part[wv] = sqrtf(ss);
  __syncthreads();
  if (t == 0)
    partials[blockIdx.x] = (s_part[0] + s_part[1]) + (s_part[2] + s_part[3]);
}

// ---------------- Kernel 5: finalize loss (deterministic tree sum) ----------------
__global__ __launch_bounds__(256) void finalize_kernel(
    const float* __restrict__ partials, float* __restrict__ out_loss)
{
  __shared__ float s[4];
  const int t = threadIdx.x;
  float p = 0.0f;
#pragma unroll
  for (int i = 0; i < 32; ++i) p += partials[t + i * 256];  // 8192, fixed order
  p = wave_sum(p);
  if ((t & 63) == 0) s[t >> 6] = p;
  __syncthreads();
  if (t == 0) out_loss[0] = 1.25f * ((s[0] + s[1]) + (s[2] + s[3])) / 32768.0f;
}

extern "C" void kernel_launch(void* const* d_in, const int* in_sizes, int n_in,
                              void* d_out, int out_size, void* d_ws, size_t ws_size,
                              hipStream_t stream) {
  const float* ze = (const float*)d_in[0];
  const float* cb = (const float*)d_in[1];

  float* out  = (float*)d_out;
  float* zq   = out;                    // 8388608
  float* sim  = out + 8388608;          // 33554432
  float* ids  = out + 41943040;         // 32768
  float* lout = out + 41975808;         // 1

  // Parked in the z_q output slot (33.5 MB, dead until zq_loss):
  //   zb   = bf16 z_e, bytes [0, 16.8M)
  //   cand = 4 MB candidate encs, bytes [16.8M, 20.8M)
  unsigned short* zb = (unsigned short*)d_out;
  float* cand = (float*)((char*)d_out + 16777216);

  // ws layout (~680 KB, under the empirically-confirmed ~800 KB floor)
  char* w = (char*)d_ws;
  unsigned short* cbb = (unsigned short*)w;      // 512 KB
  float* rsqz     = (float*)(w + 524288);        // 128 KB
  float* nse      = (float*)(w + 655360);        // 4 KB
  float* rsqe     = (float*)(w + 659456);        // 4 KB
  float* partials = (float*)(w + 663552);        // 32 KB (8192 f32)

  prep_kernel<<<8448, 256, 0, stream>>>(ze, cb, zb, cbb, rsqz, nse, rsqe);
  gemm_kernel<<<2048, 256, 0, stream>>>(zb, cbb, rsqz, rsqe, nse, sim, cand);
  select1_kernel<<<8192, 256, 0, stream>>>(ze, cb, cand, nse, ids);
  zq_loss_kernel<<<8192, 256, 0, stream>>>(ze, cb, ids, zq, partials);
  finalize_kernel<<<1, 256, 0, stream>>>(partials, lout);
}